// Round 4
// baseline (10074.833 us; speedup 1.0000x reference)
//
#include <hip/hip_runtime.h>

// Problem constants (fixed by the reference: N=65536, K=4096, D=128).
constexpr int N_PTS  = 65536;
constexpr int K_CENT = 4096;
constexpr int D_DIM  = 128;
constexpr int KB     = 8;    // centroids per k-tile (8 fp32 accumulators/thread)
constexpr int BLK    = 64;   // one wave per block; lane <-> point
constexpr int LSTR   = 130;  // LDS row stride: 2-way bank conflict max, b64-aligned

// addrspace(4) = constant: uniform-address loads select s_load (SGPR broadcast).
typedef const __attribute__((address_space(4))) float cfloat;

// ---------------------------------------------------------------------------
// Pre-kernel 1: c2[k] = sum_d coords[k][d]^2
// ---------------------------------------------------------------------------
__global__ __launch_bounds__(256) void c2_kernel(const float* __restrict__ coords,
                                                 float* __restrict__ c2) {
    int k = blockIdx.x * 256 + threadIdx.x;
    const float* c = coords + (size_t)k * D_DIM;
    float s = 0.f;
#pragma unroll
    for (int d = 0; d < D_DIM; ++d) s = fmaf(c[d], c[d], s);
    c2[k] = s;
}

// ---------------------------------------------------------------------------
// Pre-kernel 2: coordsT[d][k] = coords[k][d]  (makes k-tiles contiguous for
// s_load_dwordx8 merging in the main kernel). 2 MB once — negligible.
// ---------------------------------------------------------------------------
__global__ __launch_bounds__(256) void transpose_kernel(const float* __restrict__ coords,
                                                        float* __restrict__ coordsT) {
    int id = blockIdx.x * 256 + threadIdx.x;   // 0 .. K*32-1
    int k  = id >> 5;
    int d0 = (id & 31) << 2;
    float4 v = *(const float4*)(coords + (size_t)k * D_DIM + d0);
    coordsT[(d0 + 0) * K_CENT + k] = v.x;
    coordsT[(d0 + 1) * K_CENT + k] = v.y;
    coordsT[(d0 + 2) * K_CENT + k] = v.z;
    coordsT[(d0 + 3) * K_CENT + k] = v.w;
}

// ---------------------------------------------------------------------------
// Main kernel: one wave per block, lane <-> point. Latent rows staged in LDS
// (indexed memory — the register allocator cannot spill it; rounds 1-3 died
// trying to keep 128 floats/thread in VGPRs). Coords read at wave-uniform
// addresses from addrspace(4) -> s_load_dwordx8 -> SGPR broadcast. Inner loop
// is pure v_fmac_f32 v, s, v: 32 FMA + 2 ds_read_b64 per 4d-group.
// Running argmin over all K: ascending k + strict < = jnp first-min tie rule.
// score = c2[k] - 2*dot (x^2 per-point constant; sqrt monotone).
// ---------------------------------------------------------------------------
__global__ __launch_bounds__(BLK) void argmin_kernel(
        const float* __restrict__ latent,
        const float* __restrict__ coordsT,   // [D][K]
        const float* __restrict__ c2,        // [K]
        int* __restrict__ out) {
    __shared__ float lat[BLK * LSTR];        // 33.3 KB -> 4 blocks/CU
    const int lane = threadIdx.x;
    const int n = blockIdx.x * BLK + lane;

    // Stage this block's 64 latent rows (lane = row).
    {
        const float* lp = latent + (size_t)n * D_DIM;
        float* dst = lat + lane * LSTR;
#pragma unroll
        for (int d = 0; d < D_DIM; d += 4) {
            float4 v = *(const float4*)(lp + d);
            dst[d + 0] = v.x; dst[d + 1] = v.y; dst[d + 2] = v.z; dst[d + 3] = v.w;
        }
    }
    __syncthreads();

    cfloat* B  = (cfloat*)coordsT;
    cfloat* C2 = (cfloat*)c2;
    const float* row = lat + lane * LSTR;

    float best  = 3.4e38f;
    int   besti = 0;

    for (int k0 = 0; k0 < K_CENT; k0 += KB) {
        float a0 = 0.f, a1 = 0.f, a2 = 0.f, a3 = 0.f;
        float a4 = 0.f, a5 = 0.f, a6 = 0.f, a7 = 0.f;
#pragma unroll
        for (int d = 0; d < D_DIM; d += 4) {
            const float x0 = row[d + 0], x1 = row[d + 1];
            const float x2 = row[d + 2], x3 = row[d + 3];
            cfloat* B0 = B + (d + 0) * K_CENT + k0;   // 8 contiguous dwords each
            cfloat* B1 = B + (d + 1) * K_CENT + k0;   // -> s_load_dwordx8
            cfloat* B2 = B + (d + 2) * K_CENT + k0;
            cfloat* B3 = B + (d + 3) * K_CENT + k0;
#define FMA8(j) \
            a##j = fmaf(B0[j], x0, a##j); \
            a##j = fmaf(B1[j], x1, a##j); \
            a##j = fmaf(B2[j], x2, a##j); \
            a##j = fmaf(B3[j], x3, a##j);
            FMA8(0) FMA8(1) FMA8(2) FMA8(3) FMA8(4) FMA8(5) FMA8(6) FMA8(7)
#undef FMA8
        }
        // Epilogue: ascending j, strict < -> first minimum on ties.
#define UPD(j) { float s = fmaf(-2.f, a##j, C2[k0 + j]); \
                 if (s < best) { best = s; besti = k0 + j; } }
        UPD(0) UPD(1) UPD(2) UPD(3) UPD(4) UPD(5) UPD(6) UPD(7)
#undef UPD
    }

    out[n] = besti;
}

// ---------------------------------------------------------------------------
extern "C" void kernel_launch(void* const* d_in, const int* in_sizes, int n_in,
                              void* d_out, int out_size, void* d_ws, size_t ws_size,
                              hipStream_t stream) {
    const float* latent = (const float*)d_in[0];  // [N, D] fp32
    const float* coords = (const float*)d_in[1];  // [K, D] fp32
    int* out = (int*)d_out;                       // [N] int32 indices

    // Workspace: coordsT [D*K] | c2 [K]
    float* coordsT = (float*)d_ws;
    float* c2      = coordsT + (size_t)D_DIM * K_CENT;

    c2_kernel<<<dim3(K_CENT / 256), dim3(256), 0, stream>>>(coords, c2);
    transpose_kernel<<<dim3(K_CENT * 32 / 256), dim3(256), 0, stream>>>(coords, coordsT);
    argmin_kernel<<<dim3(N_PTS / BLK), dim3(BLK), 0, stream>>>(latent, coordsT, c2, out);
}

// Round 6
// 644.677 us; speedup vs baseline: 15.6277x; 15.6277x over previous
//
#include <hip/hip_runtime.h>

// CentroidPool: N=65536 x K=4096 x D=128 fp32, argmin_k ||x - c_k|| out (int32).
// Stage 1: f16x3-split MFMA GEMM (score = c2[k] + (-2x)·c; acc init = c2),
//          argmin fused in epilogue, tracking TOP-2 (score,idx) per point.
// Stage 2: exact fp64 rescore of the two candidates per point (near-tie
//          rescue: round-5's single flipped point = f16x3 noise ~5e-5 on a
//          near-tied pair; fp64 decides truthfully).

typedef _Float16 f16;
typedef f16  f16x8 __attribute__((ext_vector_type(8)));
typedef f16  f16x4 __attribute__((ext_vector_type(4)));
typedef float f32x4 __attribute__((ext_vector_type(4)));

constexpr int N_PTS  = 65536;
constexpr int K_CENT = 4096;
constexpr int D_DIM  = 128;
constexpr int MB     = 64;    // points per block (4 waves share them)
constexpr int KW     = 1024;  // centroids per wave (waves split K 4-ways)
constexpr int LSTR   = 136;   // LDS row stride (f16): 272 B

// ---------------------------------------------------------------------------
__global__ __launch_bounds__(256) void c2_kernel(const float* __restrict__ coords,
                                                 float* __restrict__ c2) {
    int k = blockIdx.x * 256 + threadIdx.x;
    const float* c = coords + (size_t)k * D_DIM;
    float s = 0.f;
#pragma unroll
    for (int d = 0; d < D_DIM; ++d) s = fmaf(c[d], c[d], s);
    c2[k] = s;
}

// Split coords into f16 hi/lo (x = hi + lo + O(2^-23 x)).
__global__ __launch_bounds__(256) void split_coords(const float* __restrict__ c,
                                                    f16* __restrict__ ch,
                                                    f16* __restrict__ cl) {
    int e = blockIdx.x * 256 + threadIdx.x;
    float x = c[e];
    f16 h = (f16)x;
    ch[e] = h;
    cl[e] = (f16)(x - (float)h);
}

// ---------------------------------------------------------------------------
// Stage 1. Block = 4 waves x 64 points. Latent scaled by -2, split to f16 h/l
// in LDS. Wave w scans cents [w*1024, (w+1)*1024) in 64-wide k-tiles.
// MFMA f32_16x16x32_f16: A[m=lane&15][k=quad*8+j] (LDS), B[k=quad*8+j][n=lane&15]
// (global, natural [K][D]), C/D col=lane&15 (cent), row=quad*4+reg (point).
// Top-2 by lexicographic (score, idx) == jnp first-min tie rule.
// ---------------------------------------------------------------------------
__global__ __launch_bounds__(256, 2) void argmin_mfma(
        const float* __restrict__ latent,
        const f16*   __restrict__ ch,
        const f16*   __restrict__ cl,
        const float* __restrict__ c2,
        int* __restrict__ top1,
        int* __restrict__ top2) {
    __shared__ f16 latH[MB][LSTR];
    __shared__ f16 latL[MB][LSTR];
    __shared__ float c1S[4][MB]; __shared__ int c1I[4][MB];
    __shared__ float c2S[4][MB]; __shared__ int c2I[4][MB];

    const int t    = threadIdx.x;
    const int wave = t >> 6;
    const int lane = t & 63;
    const int quad = lane >> 4;
    const int l15  = lane & 15;
    const int row0 = blockIdx.x * MB;

    {   // Stage latent: scale -2, split h/l.
        const float4* src = (const float4*)(latent + (size_t)row0 * D_DIM);
#pragma unroll
        for (int i = 0; i < 8; ++i) {
            int f  = i * 256 + t;
            int r  = f >> 5;
            int c4 = (f & 31) * 4;
            float4 v = src[f];
            float xs[4] = {v.x, v.y, v.z, v.w};
            f16x4 hv, lv;
#pragma unroll
            for (int c = 0; c < 4; ++c) {
                float x = -2.0f * xs[c];
                f16 h = (f16)x;
                hv[c] = h;
                lv[c] = (f16)(x - (float)h);
            }
            *(f16x4*)&latH[r][c4] = hv;
            *(f16x4*)&latL[r][c4] = lv;
        }
    }
    __syncthreads();

    float b1s[4][4], b2s[4][4];
    int   b1i[4][4], b2i[4][4];
#pragma unroll
    for (int m = 0; m < 4; ++m)
#pragma unroll
        for (int r = 0; r < 4; ++r) {
            b1s[m][r] = 3.4e38f; b1i[m][r] = 0x7ffffffe;
            b2s[m][r] = 3.4e38f; b2i[m][r] = 0x7fffffff;
        }

    for (int kt = 0; kt < KW / 64; ++kt) {
        const int k0 = wave * KW + kt * 64;

        f32x4 acc[4][4];
#pragma unroll
        for (int n = 0; n < 4; ++n) {
            float cv = c2[k0 + n * 16 + l15];
            f32x4 iv = {cv, cv, cv, cv};
#pragma unroll
            for (int m = 0; m < 4; ++m) acc[m][n] = iv;
        }

        for (int ds = 0; ds < 4; ++ds) {
            const int dof = ds * 32 + quad * 8;
            f16x8 ah[4], al[4], bh[4], bl[4];
#pragma unroll
            for (int n = 0; n < 4; ++n) {
                size_t off = (size_t)(k0 + n * 16 + l15) * D_DIM + dof;
                bh[n] = *(const f16x8*)(ch + off);
                bl[n] = *(const f16x8*)(cl + off);
            }
#pragma unroll
            for (int m = 0; m < 4; ++m) {
                ah[m] = *(const f16x8*)&latH[m * 16 + l15][dof];
                al[m] = *(const f16x8*)&latL[m * 16 + l15][dof];
            }
#pragma unroll
            for (int m = 0; m < 4; ++m)
#pragma unroll
                for (int n = 0; n < 4; ++n) {
                    acc[m][n] = __builtin_amdgcn_mfma_f32_16x16x32_f16(ah[m], bh[n], acc[m][n], 0, 0, 0);
                    acc[m][n] = __builtin_amdgcn_mfma_f32_16x16x32_f16(ah[m], bl[n], acc[m][n], 0, 0, 0);
                    acc[m][n] = __builtin_amdgcn_mfma_f32_16x16x32_f16(al[m], bh[n], acc[m][n], 0, 0, 0);
                }
        }

        // Top-2 insert, lexicographic (score, idx).
#pragma unroll
        for (int n = 0; n < 4; ++n) {
            int idx = k0 + n * 16 + l15;
#pragma unroll
            for (int m = 0; m < 4; ++m)
#pragma unroll
                for (int r = 0; r < 4; ++r) {
                    float s = acc[m][n][r];
                    bool lt1 = (s < b1s[m][r]) || (s == b1s[m][r] && idx < b1i[m][r]);
                    bool lt2 = (s < b2s[m][r]) || (s == b2s[m][r] && idx < b2i[m][r]);
                    float os1 = b1s[m][r]; int oi1 = b1i[m][r];
                    b1s[m][r] = lt1 ? s   : b1s[m][r];
                    b1i[m][r] = lt1 ? idx : b1i[m][r];
                    b2s[m][r] = lt1 ? os1 : (lt2 ? s   : b2s[m][r]);
                    b2i[m][r] = lt1 ? oi1 : (lt2 ? idx : b2i[m][r]);
                }
        }
    }

    // Quad butterfly: merge two sorted-2 lists per step.
#pragma unroll
    for (int m = 0; m < 4; ++m)
#pragma unroll
        for (int r = 0; r < 4; ++r) {
            float s1 = b1s[m][r], s2 = b2s[m][r];
            int   i1 = b1i[m][r], i2 = b2i[m][r];
#pragma unroll
            for (int msk = 1; msk < 16; msk <<= 1) {
                float o1s = __shfl_xor(s1, msk, 64); int o1i = __shfl_xor(i1, msk, 64);
                float o2s = __shfl_xor(s2, msk, 64); int o2i = __shfl_xor(i2, msk, 64);
                bool ow = (o1s < s1) || (o1s == s1 && o1i < i1);
                float w1s = ow ? o1s : s1; int w1i = ow ? o1i : i1;
                float aas = ow ? s1  : o1s; int aai = ow ? i1  : o1i; // loser of firsts
                float bbs = ow ? o2s : s2;  int bbi = ow ? o2i : i2;  // winner's second
                bool sw = (aas < bbs) || (aas == bbs && aai < bbi);
                s1 = w1s; i1 = w1i;
                s2 = sw ? aas : bbs; i2 = sw ? aai : bbi;
            }
            if (l15 == 0) {
                int p = m * 16 + quad * 4 + r;
                c1S[wave][p] = s1; c1I[wave][p] = i1;
                c2S[wave][p] = s2; c2I[wave][p] = i2;
            }
        }
    __syncthreads();

    if (t < MB) {
        float s1 = c1S[0][t], s2 = c2S[0][t];
        int   i1 = c1I[0][t], i2 = c2I[0][t];
#pragma unroll
        for (int w = 1; w < 4; ++w) {
            float o1s = c1S[w][t], o2s = c2S[w][t];
            int   o1i = c1I[w][t], o2i = c2I[w][t];
            bool ow = (o1s < s1) || (o1s == s1 && o1i < i1);
            float w1s = ow ? o1s : s1; int w1i = ow ? o1i : i1;
            float aas = ow ? s1  : o1s; int aai = ow ? i1  : o1i;
            float bbs = ow ? o2s : s2;  int bbi = ow ? o2i : i2;
            bool sw = (aas < bbs) || (aas == bbs && aai < bbi);
            s1 = w1s; i1 = w1i;
            s2 = sw ? aas : bbs; i2 = sw ? aai : bbi;
        }
        top1[row0 + t] = i1;
        top2[row0 + t] = i2;
    }
}

// ---------------------------------------------------------------------------
// Stage 2: exact fp64 rescore of the two candidates; true winner (idx ties ->
// smaller index). Fixes any approx flip between top-1 and top-2.
// ---------------------------------------------------------------------------
__global__ __launch_bounds__(256) void rescore(const float* __restrict__ latent,
                                               const float* __restrict__ coords,
                                               const int* __restrict__ top1,
                                               const int* __restrict__ top2,
                                               int* __restrict__ out) {
    int n = blockIdx.x * 256 + threadIdx.x;
    int i1 = top1[n], i2 = top2[n];
    const float* x  = latent + (size_t)n * D_DIM;
    const float* ca = coords + (size_t)i1 * D_DIM;
    const float* cb = coords + (size_t)i2 * D_DIM;
    double d1 = 0.0, d2 = 0.0;
#pragma unroll
    for (int d = 0; d < D_DIM; d += 4) {
        float4 xv = *(const float4*)(x + d);
        float4 av = *(const float4*)(ca + d);
        float4 bv = *(const float4*)(cb + d);
        double e;
        e = (double)xv.x - (double)av.x; d1 += e * e;
        e = (double)xv.y - (double)av.y; d1 += e * e;
        e = (double)xv.z - (double)av.z; d1 += e * e;
        e = (double)xv.w - (double)av.w; d1 += e * e;
        e = (double)xv.x - (double)bv.x; d2 += e * e;
        e = (double)xv.y - (double)bv.y; d2 += e * e;
        e = (double)xv.z - (double)bv.z; d2 += e * e;
        e = (double)xv.w - (double)bv.w; d2 += e * e;
    }
    bool second = (d2 < d1) || (d2 == d1 && i2 < i1);
    out[n] = second ? i2 : i1;
}

// ---------------------------------------------------------------------------
extern "C" void kernel_launch(void* const* d_in, const int* in_sizes, int n_in,
                              void* d_out, int out_size, void* d_ws, size_t ws_size,
                              hipStream_t stream) {
    const float* latent = (const float*)d_in[0];
    const float* coords = (const float*)d_in[1];
    int* out = (int*)d_out;

    // ws: ch [K*D] f16 | cl [K*D] f16 | c2 [K] f32 | top1 [N] i32 | top2 [N] i32
    f16*   ch = (f16*)d_ws;
    f16*   cl = ch + (size_t)K_CENT * D_DIM;
    float* c2 = (float*)(cl + (size_t)K_CENT * D_DIM);
    int*   t1 = (int*)(c2 + K_CENT);
    int*   t2 = t1 + N_PTS;

    c2_kernel<<<dim3(K_CENT / 256), dim3(256), 0, stream>>>(coords, c2);
    split_coords<<<dim3(K_CENT * D_DIM / 256), dim3(256), 0, stream>>>(coords, ch, cl);
    argmin_mfma<<<dim3(N_PTS / MB), dim3(256), 0, stream>>>(latent, ch, cl, c2, t1, t2);
    rescore<<<dim3(N_PTS / 256), dim3(256), 0, stream>>>(latent, coords, t1, t2, out);
}

// Round 7
// 404.654 us; speedup vs baseline: 24.8974x; 1.5932x over previous
//
#include <hip/hip_runtime.h>

// CentroidPool: N=65536 x K=4096 x D=128 fp32 -> argmin_k ||x - c_k|| (int32).
// Stage 1: f16x3-split MFMA GEMM (xh*ch + xh*cl + xl*ch, fp32 acc), argmin
//   fused in epilogue tracking TOP-2 (score,idx) per point via min/max + a
//   packed index reg (round-6 spilled 1.9 KB/thread: FETCH 784 MB + WRITE
//   499 MB of scratch -> HBM-bound; this round cuts live VGPRs below 128).
// Stage 2: exact fp64 rescore of the 2 candidates (near-tie rescue).

typedef _Float16 f16;
typedef f16  f16x8 __attribute__((ext_vector_type(8)));
typedef f16  f16x4 __attribute__((ext_vector_type(4)));
typedef float f32x4 __attribute__((ext_vector_type(4)));

constexpr int N_PTS  = 65536;
constexpr int K_CENT = 4096;
constexpr int D_DIM  = 128;
constexpr int MB     = 64;    // points per block (4 waves share them)
constexpr int KW     = 1024;  // centroids per wave (waves split K 4-ways)
constexpr int LSTR   = 136;   // LDS row stride (f16)

// ---------------------------------------------------------------------------
__global__ __launch_bounds__(256) void c2_kernel(const float* __restrict__ coords,
                                                 float* __restrict__ c2) {
    int k = blockIdx.x * 256 + threadIdx.x;
    const float* c = coords + (size_t)k * D_DIM;
    float s = 0.f;
#pragma unroll
    for (int d = 0; d < D_DIM; ++d) s = fmaf(c[d], c[d], s);
    c2[k] = s;
}

__global__ __launch_bounds__(256) void split_coords(const float* __restrict__ c,
                                                    f16* __restrict__ ch,
                                                    f16* __restrict__ cl) {
    int e = blockIdx.x * 256 + threadIdx.x;
    float x = c[e];
    f16 h = (f16)x;
    ch[e] = h;
    cl[e] = (f16)(x - (float)h);
}

// ---------------------------------------------------------------------------
// Stage 1. Block = 4 waves x 64 points; latent (-2x) split to f16 h/l in LDS.
// Wave w scans cents [w*1024,(w+1)*1024) in 64-wide k-tiles.
// MFMA f32_16x16x32_f16: A[m=lane&15][k=quad*8+j] (LDS), B[k][n=lane&15]
// (global [K][D]); C/D col=lane&15 (cent), row=quad*4+reg (point).
// Top-2 scores: b1=min(s,b1), b2=min(max(s,b1_old),b2).  Indices: one packed
// reg (kn1<<8)|kn2, kn=kt*4+n (wave-uniform); idx=(wave*64+kn)*16+l15.
// ---------------------------------------------------------------------------
__global__ __launch_bounds__(256, 2) void argmin_mfma(
        const float* __restrict__ latent,
        const f16*   __restrict__ ch,
        const f16*   __restrict__ cl,
        const float* __restrict__ c2v,
        int* __restrict__ top1,
        int* __restrict__ top2) {
    __shared__ f16 latH[MB][LSTR];
    __shared__ f16 latL[MB][LSTR];
    __shared__ float r1S[4][MB]; __shared__ int r1I[4][MB];
    __shared__ float r2S[4][MB]; __shared__ int r2I[4][MB];

    const int t    = threadIdx.x;
    const int wave = t >> 6;
    const int lane = t & 63;
    const int quad = lane >> 4;
    const int l15  = lane & 15;
    const int row0 = blockIdx.x * MB;

    {   // Stage latent: scale -2, split h/l.
        const float4* src = (const float4*)(latent + (size_t)row0 * D_DIM);
#pragma unroll
        for (int i = 0; i < 8; ++i) {
            int f  = i * 256 + t;
            int r  = f >> 5;
            int c4 = (f & 31) * 4;
            float4 v = src[f];
            float xs[4] = {v.x, v.y, v.z, v.w};
            f16x4 hv, lv;
#pragma unroll
            for (int c = 0; c < 4; ++c) {
                float x = -2.0f * xs[c];
                f16 h = (f16)x;
                hv[c] = h;
                lv[c] = (f16)(x - (float)h);
            }
            *(f16x4*)&latH[r][c4] = hv;
            *(f16x4*)&latL[r][c4] = lv;
        }
    }
    __syncthreads();

    float b1s[4][4], b2s[4][4];
    int   pk[4][4];
#pragma unroll
    for (int m = 0; m < 4; ++m)
#pragma unroll
        for (int r = 0; r < 4; ++r) {
            b1s[m][r] = 3.4e38f; b2s[m][r] = 3.4e38f; pk[m][r] = 0xFFFF;
        }

#pragma unroll 1
    for (int kt = 0; kt < KW / 64; ++kt) {
        const int k0 = wave * KW + kt * 64;

        // Prefetch c2 for this tile (overlaps the MFMA loop).
        float cv[4];
#pragma unroll
        for (int n = 0; n < 4; ++n) cv[n] = c2v[k0 + n * 16 + l15];

        f32x4 acc[4][4];
#pragma unroll
        for (int n = 0; n < 4; ++n)
#pragma unroll
            for (int m = 0; m < 4; ++m) acc[m][n] = (f32x4){0.f, 0.f, 0.f, 0.f};

#pragma unroll 1
        for (int ds = 0; ds < 4; ++ds) {
            const int dof = ds * 32 + quad * 8;
            f16x8 ah[4], al[4];
#pragma unroll
            for (int m = 0; m < 4; ++m) {
                ah[m] = *(const f16x8*)&latH[m * 16 + l15][dof];
                al[m] = *(const f16x8*)&latL[m * 16 + l15][dof];
            }
#pragma unroll
            for (int n = 0; n < 4; ++n) {
                size_t off = (size_t)(k0 + n * 16 + l15) * D_DIM + dof;
                f16x8 bh = *(const f16x8*)(ch + off);
                f16x8 bl = *(const f16x8*)(cl + off);
#pragma unroll
                for (int m = 0; m < 4; ++m) {
                    acc[m][n] = __builtin_amdgcn_mfma_f32_16x16x32_f16(ah[m], bh, acc[m][n], 0, 0, 0);
                    acc[m][n] = __builtin_amdgcn_mfma_f32_16x16x32_f16(ah[m], bl, acc[m][n], 0, 0, 0);
                    acc[m][n] = __builtin_amdgcn_mfma_f32_16x16x32_f16(al[m], bh, acc[m][n], 0, 0, 0);
                }
            }
        }

        // Epilogue: ascending n => ascending cent idx; strict < everywhere
        // preserves the first-minimum (jnp.argmin) rule.
#pragma unroll
        for (int n = 0; n < 4; ++n) {
            const int kn = kt * 4 + n;           // wave-uniform tile-local id
#pragma unroll
            for (int m = 0; m < 4; ++m)
#pragma unroll
                for (int r = 0; r < 4; ++r) {
                    float s = acc[m][n][r] + cv[n];
                    bool lt1 = s < b1s[m][r];
                    bool lt2 = s < b2s[m][r];
                    float hi = fmaxf(s, b1s[m][r]);
                    b1s[m][r] = fminf(s, b1s[m][r]);
                    b2s[m][r] = fminf(hi, b2s[m][r]);
                    int P = pk[m][r];
                    int A = (kn << 8) | (P >> 8);        // new first, old1 -> 2nd
                    int B = (P & 0xFF00) | kn;           // new second
                    pk[m][r] = lt1 ? A : (lt2 ? B : P);
                }
        }
    }

    // Quad butterfly: merge two sorted-2 lists per step (idx tie-break).
#pragma unroll
    for (int m = 0; m < 4; ++m)
#pragma unroll
        for (int r = 0; r < 4; ++r) {
            int P = pk[m][r];
            float s1 = b1s[m][r], s2 = b2s[m][r];
            int i1 = ((wave * 64 + (P >> 8)) << 4) | l15;
            int i2 = ((wave * 64 + (P & 0xFF)) << 4) | l15;
#pragma unroll
            for (int msk = 1; msk < 16; msk <<= 1) {
                float o1s = __shfl_xor(s1, msk, 64); int o1i = __shfl_xor(i1, msk, 64);
                float o2s = __shfl_xor(s2, msk, 64); int o2i = __shfl_xor(i2, msk, 64);
                bool ow = (o1s < s1) || (o1s == s1 && o1i < i1);
                float w1s = ow ? o1s : s1; int w1i = ow ? o1i : i1;
                float aas = ow ? s1  : o1s; int aai = ow ? i1  : o1i;
                float bbs = ow ? o2s : s2;  int bbi = ow ? o2i : i2;
                bool sw = (aas < bbs) || (aas == bbs && aai < bbi);
                s1 = w1s; i1 = w1i;
                s2 = sw ? aas : bbs; i2 = sw ? aai : bbi;
            }
            if (l15 == 0) {
                int p = m * 16 + quad * 4 + r;
                r1S[wave][p] = s1; r1I[wave][p] = i1;
                r2S[wave][p] = s2; r2I[wave][p] = i2;
            }
        }
    __syncthreads();

    if (t < MB) {
        float s1 = r1S[0][t], s2 = r2S[0][t];
        int   i1 = r1I[0][t], i2 = r2I[0][t];
#pragma unroll
        for (int w = 1; w < 4; ++w) {
            float o1s = r1S[w][t], o2s = r2S[w][t];
            int   o1i = r1I[w][t], o2i = r2I[w][t];
            bool ow = (o1s < s1) || (o1s == s1 && o1i < i1);
            float w1s = ow ? o1s : s1; int w1i = ow ? o1i : i1;
            float aas = ow ? s1  : o1s; int aai = ow ? i1  : o1i;
            float bbs = ow ? o2s : s2;  int bbi = ow ? o2i : i2;
            bool sw = (aas < bbs) || (aas == bbs && aai < bbi);
            s1 = w1s; i1 = w1i;
            s2 = sw ? aas : bbs; i2 = sw ? aai : bbi;
        }
        top1[row0 + t] = i1;
        top2[row0 + t] = i2;
    }
}

// ---------------------------------------------------------------------------
// Stage 2: exact fp64 rescore of the two candidates; true winner wins
// (idx tie -> smaller index).
// ---------------------------------------------------------------------------
__global__ __launch_bounds__(256) void rescore(const float* __restrict__ latent,
                                               const float* __restrict__ coords,
                                               const int* __restrict__ top1,
                                               const int* __restrict__ top2,
                                               int* __restrict__ out) {
    int n = blockIdx.x * 256 + threadIdx.x;
    int i1 = top1[n], i2 = top2[n];
    const float* x  = latent + (size_t)n * D_DIM;
    const float* ca = coords + (size_t)i1 * D_DIM;
    const float* cb = coords + (size_t)i2 * D_DIM;
    double d1 = 0.0, d2 = 0.0;
#pragma unroll
    for (int d = 0; d < D_DIM; d += 4) {
        float4 xv = *(const float4*)(x + d);
        float4 av = *(const float4*)(ca + d);
        float4 bv = *(const float4*)(cb + d);
        double e;
        e = (double)xv.x - (double)av.x; d1 += e * e;
        e = (double)xv.y - (double)av.y; d1 += e * e;
        e = (double)xv.z - (double)av.z; d1 += e * e;
        e = (double)xv.w - (double)av.w; d1 += e * e;
        e = (double)xv.x - (double)bv.x; d2 += e * e;
        e = (double)xv.y - (double)bv.y; d2 += e * e;
        e = (double)xv.z - (double)bv.z; d2 += e * e;
        e = (double)xv.w - (double)bv.w; d2 += e * e;
    }
    bool second = (d2 < d1) || (d2 == d1 && i2 < i1);
    out[n] = second ? i2 : i1;
}

// ---------------------------------------------------------------------------
extern "C" void kernel_launch(void* const* d_in, const int* in_sizes, int n_in,
                              void* d_out, int out_size, void* d_ws, size_t ws_size,
                              hipStream_t stream) {
    const float* latent = (const float*)d_in[0];
    const float* coords = (const float*)d_in[1];
    int* out = (int*)d_out;

    // ws: ch [K*D] f16 | cl [K*D] f16 | c2 [K] f32 | top1 [N] | top2 [N]
    f16*   ch = (f16*)d_ws;
    f16*   cl = ch + (size_t)K_CENT * D_DIM;
    float* c2 = (float*)(cl + (size_t)K_CENT * D_DIM);
    int*   t1 = (int*)(c2 + K_CENT);
    int*   t2 = t1 + N_PTS;

    c2_kernel<<<dim3(K_CENT / 256), dim3(256), 0, stream>>>(coords, c2);
    split_coords<<<dim3(K_CENT * D_DIM / 256), dim3(256), 0, stream>>>(coords, ch, cl);
    argmin_mfma<<<dim3(N_PTS / MB), dim3(256), 0, stream>>>(latent, ch, cl, c2, t1, t2);
    rescore<<<dim3(N_PTS / 256), dim3(256), 0, stream>>>(latent, coords, t1, t2, out);
}

// Round 8
// 391.872 us; speedup vs baseline: 25.7095x; 1.0326x over previous
//
#include <hip/hip_runtime.h>

// CentroidPool: N=65536 x K=4096 x D=128 fp32 -> argmin_k ||x - c_k|| (int32).
// Stage 1: f16x3-split MFMA GEMM (xh*ch + xh*cl + xl*ch, fp32 acc). Argmin
//   fused in epilogue. Scores offset +256 (strictly positive) so float bits
//   are u32-monotone; wave-local tile id kn (6 bits) packed into the low
//   mantissa bits -> top-2 insert is 6 VALU ops (round-7: ~12; VALU was the
//   critical pipe at VALUBusy/MfmaUtil = 1.64).
// Stage 2: exact fp64 rescore of the 2 candidates (near-tie rescue; also
//   covers the ~2e-3 key-truncation noise).

typedef _Float16 f16;
typedef f16  f16x8 __attribute__((ext_vector_type(8)));
typedef f16  f16x4 __attribute__((ext_vector_type(4)));
typedef float f32x4 __attribute__((ext_vector_type(4)));

constexpr int N_PTS  = 65536;
constexpr int K_CENT = 4096;
constexpr int D_DIM  = 128;
constexpr int MB     = 64;     // points per block (4 waves share them)
constexpr int KW     = 1024;   // centroids per wave (waves split K 4-ways)
constexpr int LSTR   = 136;    // LDS row stride (f16)
constexpr float SOFF = 256.0f; // score offset: c2+256-2xc > 0 always (|2xc|<~90)

// ---------------------------------------------------------------------------
// c2b[k] = sum_d coords[k][d]^2 + 256  (positive-score offset baked in)
// ---------------------------------------------------------------------------
__global__ __launch_bounds__(256) void c2_kernel(const float* __restrict__ coords,
                                                 float* __restrict__ c2b) {
    int k = blockIdx.x * 256 + threadIdx.x;
    const float* c = coords + (size_t)k * D_DIM;
    float s = 0.f;
#pragma unroll
    for (int d = 0; d < D_DIM; ++d) s = fmaf(c[d], c[d], s);
    c2b[k] = s + SOFF;
}

__global__ __launch_bounds__(256) void split_coords(const float* __restrict__ c,
                                                    f16* __restrict__ ch,
                                                    f16* __restrict__ cl) {
    int e = blockIdx.x * 256 + threadIdx.x;
    float x = c[e];
    f16 h = (f16)x;
    ch[e] = h;
    cl[e] = (f16)(x - (float)h);
}

// ---------------------------------------------------------------------------
// Stage 1. Block = 4 waves x 64 points; latent (-2x) split to f16 h/l in LDS.
// Wave w scans cents [w*1024,(w+1)*1024) in 64-wide k-tiles.
// MFMA f32_16x16x32_f16: A[m=lane&15][k=quad*8+j] (LDS), B[k][n=lane&15]
// (global [K][D]); C/D col=lane&15 (cent), row=quad*4+reg (point).
// key = (bits(score+c2b) & ~63) | kn ; top-2 = u32 min/max chain.
// cent = (wave*64 + kn)*16 + l15, reconstructed before the butterfly.
// ---------------------------------------------------------------------------
__global__ __launch_bounds__(256, 2) void argmin_mfma(
        const float* __restrict__ latent,
        const f16*   __restrict__ ch,
        const f16*   __restrict__ cl,
        const float* __restrict__ c2b,
        int* __restrict__ top1,
        int* __restrict__ top2) {
    __shared__ f16 latH[MB][LSTR];
    __shared__ f16 latL[MB][LSTR];
    __shared__ unsigned r1K[4][MB]; __shared__ int r1I[4][MB];
    __shared__ unsigned r2K[4][MB]; __shared__ int r2I[4][MB];

    const int t    = threadIdx.x;
    const int wave = t >> 6;
    const int lane = t & 63;
    const int quad = lane >> 4;
    const int l15  = lane & 15;
    const int row0 = blockIdx.x * MB;

    {   // Stage latent: scale -2, split h/l.
        const float4* src = (const float4*)(latent + (size_t)row0 * D_DIM);
#pragma unroll
        for (int i = 0; i < 8; ++i) {
            int f  = i * 256 + t;
            int r  = f >> 5;
            int c4 = (f & 31) * 4;
            float4 v = src[f];
            float xs[4] = {v.x, v.y, v.z, v.w};
            f16x4 hv, lv;
#pragma unroll
            for (int c = 0; c < 4; ++c) {
                float x = -2.0f * xs[c];
                f16 h = (f16)x;
                hv[c] = h;
                lv[c] = (f16)(x - (float)h);
            }
            *(f16x4*)&latH[r][c4] = hv;
            *(f16x4*)&latL[r][c4] = lv;
        }
    }
    __syncthreads();

    unsigned b1[4][4], b2[4][4];
#pragma unroll
    for (int m = 0; m < 4; ++m)
#pragma unroll
        for (int r = 0; r < 4; ++r) { b1[m][r] = 0xFFFFFFFFu; b2[m][r] = 0xFFFFFFFFu; }

#pragma unroll 1
    for (int kt = 0; kt < KW / 64; ++kt) {
        const int k0 = wave * KW + kt * 64;

        float cv[4];
#pragma unroll
        for (int n = 0; n < 4; ++n) cv[n] = c2b[k0 + n * 16 + l15];

        f32x4 acc[4][4];
#pragma unroll
        for (int n = 0; n < 4; ++n)
#pragma unroll
            for (int m = 0; m < 4; ++m) acc[m][n] = (f32x4){0.f, 0.f, 0.f, 0.f};

#pragma unroll 1
        for (int ds = 0; ds < 4; ++ds) {
            const int dof = ds * 32 + quad * 8;
            f16x8 ah[4], al[4];
#pragma unroll
            for (int m = 0; m < 4; ++m) {
                ah[m] = *(const f16x8*)&latH[m * 16 + l15][dof];
                al[m] = *(const f16x8*)&latL[m * 16 + l15][dof];
            }
#pragma unroll
            for (int n = 0; n < 4; ++n) {
                size_t off = (size_t)(k0 + n * 16 + l15) * D_DIM + dof;
                f16x8 bh = *(const f16x8*)(ch + off);
                f16x8 bl = *(const f16x8*)(cl + off);
#pragma unroll
                for (int m = 0; m < 4; ++m) {
                    acc[m][n] = __builtin_amdgcn_mfma_f32_16x16x32_f16(ah[m], bh, acc[m][n], 0, 0, 0);
                    acc[m][n] = __builtin_amdgcn_mfma_f32_16x16x32_f16(ah[m], bl, acc[m][n], 0, 0, 0);
                    acc[m][n] = __builtin_amdgcn_mfma_f32_16x16x32_f16(al[m], bh, acc[m][n], 0, 0, 0);
                }
            }
        }

        // Epilogue: 6 VALU ops per slot (add, and, or, max, min, min).
#pragma unroll
        for (int n = 0; n < 4; ++n) {
            const unsigned kn = (unsigned)(kt * 4 + n);   // wave-uniform, 6 bits
#pragma unroll
            for (int m = 0; m < 4; ++m)
#pragma unroll
                for (int r = 0; r < 4; ++r) {
                    float s = acc[m][n][r] + cv[n];
                    unsigned key = (__float_as_uint(s) & 0xFFFFFFC0u) | kn;
                    unsigned hi = key > b1[m][r] ? key : b1[m][r];
                    b1[m][r] = key < b1[m][r] ? key : b1[m][r];
                    b2[m][r] = hi  < b2[m][r] ? hi  : b2[m][r];
                }
        }
    }

    // Quad butterfly: merge two sorted-2 (key,idx) lists per step.
#pragma unroll
    for (int m = 0; m < 4; ++m)
#pragma unroll
        for (int r = 0; r < 4; ++r) {
            unsigned k1 = b1[m][r], k2 = b2[m][r];
            int i1 = ((wave * 64 + (int)(k1 & 63u)) << 4) | l15;
            int i2 = ((wave * 64 + (int)(k2 & 63u)) << 4) | l15;
#pragma unroll
            for (int msk = 1; msk < 16; msk <<= 1) {
                unsigned ok1 = (unsigned)__shfl_xor((int)k1, msk, 64);
                int      oi1 = __shfl_xor(i1, msk, 64);
                unsigned ok2 = (unsigned)__shfl_xor((int)k2, msk, 64);
                int      oi2 = __shfl_xor(i2, msk, 64);
                bool ow = ok1 < k1;
                unsigned w1k = ow ? ok1 : k1; int w1i = ow ? oi1 : i1;
                unsigned lsk = ow ? k1 : ok1; int lsi = ow ? i1 : oi1;   // loser of firsts
                unsigned wsk = ow ? ok2 : k2; int wsi = ow ? oi2 : i2;   // winner's second
                bool sw = lsk < wsk;
                k1 = w1k; i1 = w1i;
                k2 = sw ? lsk : wsk; i2 = sw ? lsi : wsi;
            }
            if (l15 == 0) {
                int p = m * 16 + quad * 4 + r;
                r1K[wave][p] = k1; r1I[wave][p] = i1;
                r2K[wave][p] = k2; r2I[wave][p] = i2;
            }
        }
    __syncthreads();

    if (t < MB) {
        unsigned k1 = r1K[0][t], k2 = r2K[0][t];
        int      i1 = r1I[0][t], i2 = r2I[0][t];
#pragma unroll
        for (int w = 1; w < 4; ++w) {
            unsigned ok1 = r1K[w][t], ok2 = r2K[w][t];
            int      oi1 = r1I[w][t], oi2 = r2I[w][t];
            bool ow = ok1 < k1;
            unsigned w1k = ow ? ok1 : k1; int w1i = ow ? oi1 : i1;
            unsigned lsk = ow ? k1 : ok1; int lsi = ow ? i1 : oi1;
            unsigned wsk = ow ? ok2 : k2; int wsi = ow ? oi2 : i2;
            bool sw = lsk < wsk;
            k1 = w1k; i1 = w1i;
            k2 = sw ? lsk : wsk; i2 = sw ? lsi : wsi;
        }
        top1[row0 + t] = i1;
        top2[row0 + t] = i2;
    }
}

// ---------------------------------------------------------------------------
// Stage 2: exact fp64 rescore of the two candidates; true winner wins
// (idx tie -> smaller index).
// ---------------------------------------------------------------------------
__global__ __launch_bounds__(256) void rescore(const float* __restrict__ latent,
                                               const float* __restrict__ coords,
                                               const int* __restrict__ top1,
                                               const int* __restrict__ top2,
                                               int* __restrict__ out) {
    int n = blockIdx.x * 256 + threadIdx.x;
    int i1 = top1[n], i2 = top2[n];
    const float* x  = latent + (size_t)n * D_DIM;
    const float* ca = coords + (size_t)i1 * D_DIM;
    const float* cb = coords + (size_t)i2 * D_DIM;
    double d1 = 0.0, d2 = 0.0;
#pragma unroll
    for (int d = 0; d < D_DIM; d += 4) {
        float4 xv = *(const float4*)(x + d);
        float4 av = *(const float4*)(ca + d);
        float4 bv = *(const float4*)(cb + d);
        double e;
        e = (double)xv.x - (double)av.x; d1 += e * e;
        e = (double)xv.y - (double)av.y; d1 += e * e;
        e = (double)xv.z - (double)av.z; d1 += e * e;
        e = (double)xv.w - (double)av.w; d1 += e * e;
        e = (double)xv.x - (double)bv.x; d2 += e * e;
        e = (double)xv.y - (double)bv.y; d2 += e * e;
        e = (double)xv.z - (double)bv.z; d2 += e * e;
        e = (double)xv.w - (double)bv.w; d2 += e * e;
    }
    bool second = (d2 < d1) || (d2 == d1 && i2 < i1);
    out[n] = second ? i2 : i1;
}

// ---------------------------------------------------------------------------
extern "C" void kernel_launch(void* const* d_in, const int* in_sizes, int n_in,
                              void* d_out, int out_size, void* d_ws, size_t ws_size,
                              hipStream_t stream) {
    const float* latent = (const float*)d_in[0];
    const float* coords = (const float*)d_in[1];
    int* out = (int*)d_out;

    // ws: ch [K*D] f16 | cl [K*D] f16 | c2b [K] f32 | top1 [N] | top2 [N]
    f16*   ch  = (f16*)d_ws;
    f16*   cl  = ch + (size_t)K_CENT * D_DIM;
    float* c2b = (float*)(cl + (size_t)K_CENT * D_DIM);
    int*   t1  = (int*)(c2b + K_CENT);
    int*   t2  = t1 + N_PTS;

    c2_kernel<<<dim3(K_CENT / 256), dim3(256), 0, stream>>>(coords, c2b);
    split_coords<<<dim3(K_CENT * D_DIM / 256), dim3(256), 0, stream>>>(coords, ch, cl);
    argmin_mfma<<<dim3(N_PTS / MB), dim3(256), 0, stream>>>(latent, ch, cl, c2b, t1, t2);
    rescore<<<dim3(N_PTS / 256), dim3(256), 0, stream>>>(latent, coords, t1, t2, out);
}